// Round 1
// 138.090 us; speedup vs baseline: 1.0131x; 1.0131x over previous
//
#include <hip/hip_runtime.h>

// Matcher: anchors [N=1024,2] fp32, gt_boxes [B=128,M=256,4] fp32.
// Both boxes are origin-centered, so:
//   iw = min(aw, gtw), ih = min(ah, gth)
//   iou = iw*ih / (aw*ah + gtw*gth - iw*ih)
// Outputs (concatenated float32): matches [B,M] (argmax over N, first-max
// semantics), then ious [B,N,M].
//
// Write-BW-bound (~134 MB out). v2 layout: block = (b, n-quarter) so every
// wave stores FULL 1 KB rows (float4/lane, 64 lanes * 16 B) and streams a
// contiguous 32 KB run — vs v1's 512 B half-row chunks at stride 1024.
// Grid 512 = 2 blocks/CU (16 waves/CU). Cross-block argmax over the 4
// n-quarters goes through a 1 MB workspace + a tiny reduce kernel.

#define N_ANCH 1024
#define B_SZ   128
#define M_SZ   256
#define NQ     4                 // n-quarters per b
#define NPB    (N_ANCH / NQ)     // 256 n rows per block
#define NWAVES 8
#define NPW    (NPB / NWAVES)    // 32 n rows per wave

__global__ __launch_bounds__(512) void iou_kernel(
    const float* __restrict__ anchors,   // [N,2]
    const float* __restrict__ gt,        // [B,M,4]
    float* __restrict__ out,             // [B*M] matches ++ [B,N,M] ious
    float* __restrict__ ws_val,          // [B*NQ, M] partial max
    int*   __restrict__ ws_idx)          // [B*NQ, M] partial argmax
{
    __shared__ float2 s_anch[NPB];          // 2 KB
    __shared__ float  s_val[NWAVES * M_SZ]; // 8 KB
    __shared__ int    s_idx[NWAVES * M_SZ]; // 8 KB

    const int tid  = threadIdx.x;
    const int lane = tid & 63;
    const int w    = tid >> 6;
    const int b    = blockIdx.x >> 2;
    const int q    = blockIdx.x & 3;

    // Stage this block's 256 anchors (wave-uniform broadcast reads later).
    if (tid < NPB) s_anch[tid] = ((const float2*)anchors)[q * NPB + tid];

    // Per-lane gt boxes: 4 adjacent m (64 B contiguous per lane).
    const int m0 = lane * 4;
    const float4* g4 = (const float4*)gt + b * M_SZ + m0;
    float gtw[4], gth[4], areab[4];
    #pragma unroll
    for (int j = 0; j < 4; ++j) {
        float4 g = g4[j];
        gtw[j]   = g.z - g.x;
        gth[j]   = g.w - g.y;
        areab[j] = gtw[j] * gth[j];
    }

    __syncthreads();

    float bv[4] = {-1.f, -1.f, -1.f, -1.f};
    int   bi[4] = {0, 0, 0, 0};

    const int n_begin = q * NPB + w * NPW;
    float* __restrict__ row = out + (size_t)B_SZ * M_SZ
                            + (size_t)(b * N_ANCH + n_begin) * M_SZ + m0;
    const int a_base = w * NPW;

    // One IoU; J is a compile-time constant, DST an l-value in float4 r.
    #define IOU1(J, DST)                                                    \
    {                                                                       \
        float iw    = fminf(a.x, gtw[J]);                                   \
        float ih    = fminf(a.y, gth[J]);                                   \
        float inter = iw * ih;                                              \
        float iou   = __fdividef(inter, areaa + areab[J] - inter);          \
        DST = iou;                                                          \
        if (iou > bv[J]) { bv[J] = iou; bi[J] = n; }  /* strict >: first */ \
    }

    #pragma unroll 4
    for (int i = 0; i < NPW; ++i) {
        const int n = n_begin + i;
        float2 a = s_anch[a_base + i];      // wave-uniform -> LDS broadcast
        float areaa = a.x * a.y;
        float4 r;
        IOU1(0, r.x)
        IOU1(1, r.y)
        IOU1(2, r.z)
        IOU1(3, r.w)
        *(float4*)row = r;                  // full-row 16 B/lane store
        row += M_SZ;                        // next n row (+1 KB, contiguous)
    }
    #undef IOU1

    // Per-wave partials -> LDS.
    #pragma unroll
    for (int j = 0; j < 4; ++j) {
        s_val[w * M_SZ + m0 + j] = bv[j];
        s_idx[w * M_SZ + m0 + j] = bi[j];
    }
    __syncthreads();

    // Reduce 8 wave-partials per m. Waves are in ascending-n order; strict >
    // preserves argmax first-occurrence semantics.
    if (tid < M_SZ) {
        float v  = s_val[tid];
        int   ix = s_idx[tid];
        #pragma unroll
        for (int ww = 1; ww < NWAVES; ++ww) {
            float v2 = s_val[ww * M_SZ + tid];
            if (v2 > v) { v = v2; ix = s_idx[ww * M_SZ + tid]; }
        }
        ws_val[(b * NQ + q) * M_SZ + tid] = v;
        ws_idx[(b * NQ + q) * M_SZ + tid] = ix;
    }
}

// Combine the NQ per-quarter partials (ascending q + strict > = first max).
__global__ __launch_bounds__(512) void match_kernel(
    const float* __restrict__ ws_val,
    const int*   __restrict__ ws_idx,
    float* __restrict__ out)
{
    const int t = blockIdx.x * 512 + threadIdx.x;   // 0 .. B*M-1
    const int b = t >> 8;            // M_SZ == 256
    const int m = t & (M_SZ - 1);
    const int base = b * NQ * M_SZ + m;
    float v  = ws_val[base];
    int   ix = ws_idx[base];
    #pragma unroll
    for (int q = 1; q < NQ; ++q) {
        float v2 = ws_val[base + q * M_SZ];
        if (v2 > v) { v = v2; ix = ws_idx[base + q * M_SZ]; }
    }
    out[t] = (float)ix;
}

extern "C" void kernel_launch(void* const* d_in, const int* in_sizes, int n_in,
                              void* d_out, int out_size, void* d_ws, size_t ws_size,
                              hipStream_t stream) {
    const float* anchors = (const float*)d_in[0];   // [1024,2]
    const float* gt      = (const float*)d_in[1];   // [128,256,4]
    float* out = (float*)d_out;

    float* ws_val = (float*)d_ws;
    int*   ws_idx = (int*)((char*)d_ws
                   + (size_t)B_SZ * NQ * M_SZ * sizeof(float));

    iou_kernel<<<dim3(B_SZ * NQ), dim3(512), 0, stream>>>(
        anchors, gt, out, ws_val, ws_idx);
    match_kernel<<<dim3(B_SZ * M_SZ / 512), dim3(512), 0, stream>>>(
        ws_val, ws_idx, out);
}